// Round 6
// baseline (2305.474 us; speedup 1.0000x reference)
//
#include <hip/hip_runtime.h>

#define B 8
#define N 16384
#define C_IN 32
#define P 1024

typedef float v2f __attribute__((ext_vector_type(2)));
typedef unsigned long long ull;

// ---------------------------------------------------------------------------
// FPS: one block per batch, 1024 threads, 16 points/thread as 8 index-pairs.
// R6: R5 calibration -> regime is VALU issue + dep-latency + DS pipe, all
// phase-locked by the per-iter barrier. Cuts:
//  - v_pk_add/mul_f32 (1-instr asm): distance math 8 -> 4 ops/point.
//    Bitwise-exact: pk ops are IEEE rn; x-c == x+(-c) exactly (sign-xor neg).
//  - SoA LDS sx[]/sy[] + ds_read_b128: 8 reads/wave/iter (was 16), data
//    arrives pre-packed for pk. One base reg, offsets fit 16-bit imm.
//  - per-group compute: peak regs ~64 (no spills); z-term consumes the late
//    scalar cz load ~10 instrs after issue -> hidden.
//  - capture msel (index) not coords; coords re-read once at end (same bits).
// R5's reduce/key/atomic/single-barrier kept verbatim:
//   key = (P-1-iter)<<46 | ~bits(val)<<14 | n  -> min-key == numpy first-max.
// Thread t owns points n = 4t + 4096*i + e (i=0..3, e=0..3), slot code
// s = ascending-n order; strict '>' chain keeps smallest n on ties.
// ---------------------------------------------------------------------------
#define R8(OP) OP(0) OP(1) OP(2) OP(3) OP(4) OP(5) OP(6) OP(7)

__device__ __forceinline__ v2f pk_add(v2f a, v2f b) {
  v2f d; asm("v_pk_add_f32 %0, %1, %2" : "=v"(d) : "v"(a), "v"(b)); return d;
}
__device__ __forceinline__ v2f pk_mul(v2f a, v2f b) {
  v2f d; asm("v_pk_mul_f32 %0, %1, %2" : "=v"(d) : "v"(a), "v"(b)); return d;
}
__device__ __forceinline__ float negf(float x) {
  return __int_as_float(__float_as_int(x) ^ 0x80000000);
}

// one max-reduce level via DPP (xor1/xor2/xor4/xor8 patterns)
template <int CTRL>
__device__ __forceinline__ float dpp_fmax(float v) {
  float o = __int_as_float(__builtin_amdgcn_update_dpp(
      __float_as_int(v), __float_as_int(v), CTRL, 0xF, 0xF, false));
  return fmaxf(v, o);
}

__global__ __launch_bounds__(1024)
void fps_kernel(const float* __restrict__ xyz, float* __restrict__ new_xyz)
{
  __shared__ __align__(16) float sx[N];      // 64 KiB
  __shared__ __align__(16) float sy[N];      // 64 KiB
  __shared__ ull slot[2];                    // argmax key, parity-alternating

  const int b = blockIdx.x;
  const int t = threadIdx.x;
  const float* xb = xyz + (size_t)b * (N * 3);

  if (t == 0) { slot[0] = ~0ull; slot[1] = ~0ull; }

  // pair j (j=0..7) = points {n0, n0+1}, n0 = 4t + 4096*(j>>1) + 2*(j&1)
#define FPS_DECL(j) v2f pzp##j, dmp##j; dmp##j.x = 1e10f; dmp##j.y = 1e10f;
  R8(FPS_DECL)
#define FPS_LOADP(j) {                                                         \
    const int n0 = (t << 2) + ((j >> 1) << 12) + ((j & 1) << 1);               \
    const float2 ld0 = *(const float2*)&xb[(size_t)n0 * 3 + 0]; /* x0,y0 */    \
    const float2 ld1 = *(const float2*)&xb[(size_t)n0 * 3 + 2]; /* z0,x1 */    \
    const float2 ld2 = *(const float2*)&xb[(size_t)n0 * 3 + 4]; /* y1,z1 */    \
    sx[n0]     = ld0.x;  sy[n0]     = ld0.y;                                   \
    sx[n0 + 1] = ld1.y;  sy[n0 + 1] = ld2.x;                                   \
    pzp##j.x   = ld1.x;  pzp##j.y   = ld2.y;                                   \
    asm volatile("" : "+v"(pzp##j)); }
  R8(FPS_LOADP)

  // bpermute lane selectors for the xor16 / xor32 reduce levels
  const int bpa16 = ((t & 63) ^ 16) << 2;
  const int bpa32 = ((t & 63) ^ 32) << 2;

  float cz = xb[2];                 // z of point 0
  __syncthreads();
  float cx = sx[0], cy = sy[0];
  int sel = 0, msel = 0;

  for (int iter = 0; iter < P; ++iter) {
    // thread `iter` records the selected index; coords re-read at the end
    msel = (t == iter) ? sel : msel;
    if (iter == P - 1) break;

    v2f cxx, cyy, czz;
    { float v = negf(cx); cxx.x = v; cxx.y = v; }
    { float v = negf(cy); cyy.x = v; cyy.y = v; }
    { float v = negf(cz); czz.x = v; czz.y = v; }

    float bestv = -1.0f;
    int   s = 0;

    // pair step: d = ((dx*dx + dy*dy) + dz*dz), all rn, bitwise == numpy
#define FPS_PAIR(xa, ya, j, s0, s1) {                                          \
      v2f dx = pk_add(xa, cxx), dy = pk_add(ya, cyy);                          \
      v2f sq = pk_add(pk_mul(dx, dx), pk_mul(dy, dy));                         \
      v2f dz = pk_add(pzp##j, czz);                                            \
      v2f dd = pk_add(sq, pk_mul(dz, dz));                                     \
      dmp##j.x = fminf(dmp##j.x, dd.x);                                        \
      dmp##j.y = fminf(dmp##j.y, dd.y);                                        \
      bool b0 = dmp##j.x > bestv;                                              \
      bestv = b0 ? dmp##j.x : bestv;  s = b0 ? (s0) : s;                       \
      bool b1 = dmp##j.y > bestv;                                              \
      bestv = b1 ? dmp##j.y : bestv;  s = b1 ? (s1) : s; }

    // group i: one b128 x-load + one b128 y-load -> pairs 2i (lo), 2i+1 (hi)
#define FPS_GROUP(i, ja, jb) {                                                 \
      const float4 qx = *(const float4*)&sx[(t << 2) + ((i) << 12)];           \
      const float4 qy = *(const float4*)&sy[(t << 2) + ((i) << 12)];           \
      v2f xl; xl.x = qx.x; xl.y = qx.y;  v2f yl; yl.x = qy.x; yl.y = qy.y;     \
      v2f xh; xh.x = qx.z; xh.y = qx.w;  v2f yh; yh.x = qy.z; yh.y = qy.w;     \
      FPS_PAIR(xl, yl, ja, 2 * (ja), 2 * (ja) + 1)                             \
      FPS_PAIR(xh, yh, jb, 2 * (jb), 2 * (jb) + 1) }

    FPS_GROUP(0, 0, 1)
    FPS_GROUP(1, 2, 3)
    FPS_GROUP(2, 4, 5)
    FPS_GROUP(3, 6, 7)

    // value-only wave max: 4 DPP levels + bpermute xor16 + bpermute xor32
    float wm = bestv;
    wm = dpp_fmax<0xB1>(wm);    // quad_perm xor1
    wm = dpp_fmax<0x4E>(wm);    // quad_perm xor2
    wm = dpp_fmax<0x141>(wm);   // row_half_mirror (xor4)
    wm = dpp_fmax<0x140>(wm);   // row_mirror (xor8)
    wm = fmaxf(wm, __int_as_float(
        __builtin_amdgcn_ds_bpermute(bpa16, __float_as_int(wm))));
    wm = fmaxf(wm, __int_as_float(
        __builtin_amdgcn_ds_bpermute(bpa32, __float_as_int(wm))));

    // candidates (>=1 lane/wave) race via order-encoding key; min key wins.
    if (bestv == wm) {
      int nn = (t << 2) + ((s & 12) << 10) + (s & 3);        // 14 bits
      unsigned inv = ~__float_as_uint(bestv);                // desc in val
      ull key = ((ull)(unsigned)(P - 1 - iter) << 46) |
                ((ull)inv << 14) | (ull)(unsigned)nn;
      atomicMin(&slot[iter & 1], key);
    }
    __syncthreads();

    ull k = slot[iter & 1];
    sel = __builtin_amdgcn_readfirstlane((int)((unsigned)k & 0x3FFFu));
    cx = sx[sel];                   // uniform addr -> LDS broadcast
    cy = sy[sel];
    cz = xb[(size_t)sel * 3 + 2];   // uniform scalar load; consumed late
  }

  // thread t holds the selected index of iteration t; emit original bits
  {
    const int n = msel;
    size_t o = ((size_t)b * P + t) * 3;
    new_xyz[o + 0] = sx[n];
    new_xyz[o + 1] = sy[n];
    new_xyz[o + 2] = xb[(size_t)n * 3 + 2];
  }
#undef FPS_DECL
#undef FPS_LOADP
#undef FPS_PAIR
#undef FPS_GROUP
}

// ---------------------------------------------------------------------------
// Ball query, both radii in one pass. One wave per (b,p). Reproduces the
// reference's gemm-form dist2 bitwise: (qq + xx) - 2*((cx*x+cy*y)+cz*z).
// First-nsample-in-index-order via ballot + prefix popcount; pad = first hit.
// ---------------------------------------------------------------------------
__global__ __launch_bounds__(256) void ballq_kernel(
    const float* __restrict__ xyz, const float* __restrict__ new_xyz,
    int* __restrict__ idx0, int* __restrict__ idx1)
{
  const int wid  = blockIdx.x * 4 + (threadIdx.x >> 6);
  const int lane = threadIdx.x & 63;
  const int b = wid >> 10;
  const int p = wid & (P - 1);
  const float* xb = xyz + (size_t)b * (N * 3);
  const size_t bp = (size_t)b * P + p;
  const float cx = new_xyz[bp * 3 + 0];
  const float cy = new_xyz[bp * 3 + 1];
  const float cz = new_xyz[bp * 3 + 2];
  const float qv = __fadd_rn(__fadd_rn(__fmul_rn(cx, cx), __fmul_rn(cy, cy)),
                             __fmul_rn(cz, cz));
  int* __restrict__ o0 = idx0 + bp * 16;
  int* __restrict__ o1 = idx1 + bp * 32;

  int c0 = 0, c1 = 0, f0 = 0, f1 = 0;
  const unsigned long long below = (1ull << lane) - 1ull;

  for (int base = 0; base < N; base += 64) {
    int n = base + lane;
    float x = xb[n * 3 + 0], y = xb[n * 3 + 1], z = xb[n * 3 + 2];
    float xxv = __fadd_rn(__fadd_rn(__fmul_rn(x, x), __fmul_rn(y, y)),
                          __fmul_rn(z, z));
    float dot = __fadd_rn(__fadd_rn(__fmul_rn(cx, x), __fmul_rn(cy, y)),
                          __fmul_rn(cz, z));
    float d2 = __fsub_rn(__fadd_rn(qv, xxv), __fmul_rn(2.0f, dot));
    unsigned long long m0 = __ballot(d2 < 0.25f);
    unsigned long long m1 = __ballot(d2 < 1.0f);
    if (c0 == 0 && m0) f0 = base + __builtin_ctzll(m0);
    if (c1 == 0 && m1) f1 = base + __builtin_ctzll(m1);
    if ((m0 >> lane) & 1ull) {
      int pos = c0 + (int)__builtin_popcountll(m0 & below);
      if (pos < 16) o0[pos] = n;
    }
    if ((m1 >> lane) & 1ull) {
      int pos = c1 + (int)__builtin_popcountll(m1 & below);
      if (pos < 32) o1[pos] = n;
    }
    c0 = min(16, c0 + (int)__builtin_popcountll(m0));
    c1 = min(32, c1 + (int)__builtin_popcountll(m1));
    if (c0 >= 16 && c1 >= 32) break;
  }
  for (int s = c0 + lane; s < 16; s += 64) o0[s] = f0;
  for (int s = c1 + lane; s < 32; s += 64) o1[s] = f1;
}

// ---------------------------------------------------------------------------
// Fused grouping + conv1(+BN+ReLU) + conv2(+BN+ReLU) + max over samples.
// Block = 256 threads handles 8 points; weights staged in LDS once per block.
// out layout: (B, 192, P) at d_out + B*P*3, branch writes CH_OFF..CH_OFF+C2.
// ---------------------------------------------------------------------------
template <int S, int C1, int C2, int CH_OFF>
__global__ __launch_bounds__(256) void mlp_kernel(
    const float* __restrict__ xyz, const float* __restrict__ feats,
    const float* __restrict__ new_xyz, const int* __restrict__ idx,
    const float* __restrict__ w1, const float* __restrict__ s1,
    const float* __restrict__ b1, const float* __restrict__ w2,
    const float* __restrict__ s2, const float* __restrict__ b2,
    float* __restrict__ out)
{
  static_assert((C1 * S) % 256 == 0 && (C2 * S) % 256 == 0, "mapping");
  __shared__ float wl1[35][C1];     // wl1[c][o] = w1[o][c]
  __shared__ float wl2[C1][C2];     // wl2[c][o] = w2[o][c]
  __shared__ float sb1[2][C1];
  __shared__ float sb2[2][C2];
  __shared__ float xs[35][S];
  __shared__ float o1s[C1][S];
  __shared__ float pm[256];

  const int tid = threadIdx.x;
  for (int i = tid; i < 35 * C1; i += 256) {
    int o = i % C1, c = i / C1;
    wl1[c][o] = w1[o * 35 + c];
  }
  for (int i = tid; i < C1 * C2; i += 256) {
    int o = i % C2, c = i / C2;
    wl2[c][o] = w2[o * C1 + c];
  }
  if (tid < C1) { sb1[0][tid] = s1[tid]; sb1[1][tid] = b1[tid]; }
  if (tid < C2) { sb2[0][tid] = s2[tid]; sb2[1][tid] = b2[tid]; }

  const int b  = blockIdx.x / (P / 8);
  const int p0 = (blockIdx.x % (P / 8)) * 8;
  const float* xb = xyz + (size_t)b * (N * 3);
  const float* fb = feats + (size_t)b * (C_IN * N);
  __syncthreads();

  for (int pi = 0; pi < 8; ++pi) {
    const int p = p0 + pi;
    const size_t bp = (size_t)b * P + p;
    const int* ip = idx + bp * S;
    const float cx = new_xyz[bp * 3 + 0];
    const float cy = new_xyz[bp * 3 + 1];
    const float cz = new_xyz[bp * 3 + 2];
    // gather grouped input (35, S): xyz-diff channels 0..2, features 3..34
    for (int i = tid; i < 35 * S; i += 256) {
      int c = i / S, s = i % S;
      int n = ip[s];
      float v;
      if (c == 0)      v = xb[n * 3 + 0] - cx;
      else if (c == 1) v = xb[n * 3 + 1] - cy;
      else if (c == 2) v = xb[n * 3 + 2] - cz;
      else             v = fb[(size_t)(c - 3) * N + n];
      xs[c][s] = v;
    }
    __syncthreads();
    // layer 1: out1[o][s] = relu(dot(w1[o], x[:,s]) * s1[o] + b1[o])
    {
      constexpr int OPT = (C1 * S) / 256;
      const int s  = tid % S;
      const int ob = (tid / S) * OPT;
      float acc[OPT];
#pragma unroll
      for (int j = 0; j < OPT; ++j) acc[j] = 0.0f;
      for (int c = 0; c < 35; ++c) {
        float xv = xs[c][s];
#pragma unroll
        for (int j = 0; j < OPT; ++j) acc[j] = fmaf(xv, wl1[c][ob + j], acc[j]);
      }
#pragma unroll
      for (int j = 0; j < OPT; ++j) {
        float v = fmaf(acc[j], sb1[0][ob + j], sb1[1][ob + j]);
        o1s[ob + j][s] = fmaxf(v, 0.0f);
      }
    }
    __syncthreads();
    // layer 2 + max over s
    {
      constexpr int NS = (C2 * S) / 256;
      const int o2 = tid % C2;
      const int sb = (tid / C2) * NS;
      float acc[NS];
#pragma unroll
      for (int j = 0; j < NS; ++j) acc[j] = 0.0f;
      for (int c = 0; c < C1; ++c) {
        float wv = wl2[c][o2];
#pragma unroll
        for (int j = 0; j < NS; ++j) acc[j] = fmaf(wv, o1s[c][sb + j], acc[j]);
      }
      const float scale = sb2[0][o2], bias = sb2[1][o2];
      float m = 0.0f;  // relu floor: max over relu(v) == max(0, max v)
#pragma unroll
      for (int j = 0; j < NS; ++j) {
        float v = fmaf(acc[j], scale, bias);
        m = fmaxf(m, v);
      }
      pm[tid] = m;
      __syncthreads();
      if (tid < C2) {
        float mm = pm[tid];
#pragma unroll
        for (int g = 1; g < 256 / C2; ++g) mm = fmaxf(mm, pm[tid + g * C2]);
        out[((size_t)b * 192 + CH_OFF + tid) * P + p] = mm;
      }
    }
    __syncthreads();
  }
}

extern "C" void kernel_launch(void* const* d_in, const int* in_sizes, int n_in,
                              void* d_out, int out_size, void* d_ws, size_t ws_size,
                              hipStream_t stream) {
  const float* xyz   = (const float*)d_in[0];
  const float* feats = (const float*)d_in[1];
  const float* w0_0 = (const float*)d_in[2];
  const float* s0_0 = (const float*)d_in[3];
  const float* b0_0 = (const float*)d_in[4];
  const float* w0_1 = (const float*)d_in[5];
  const float* s0_1 = (const float*)d_in[6];
  const float* b0_1 = (const float*)d_in[7];
  const float* w1_0 = (const float*)d_in[8];
  const float* s1_0 = (const float*)d_in[9];
  const float* b1_0 = (const float*)d_in[10];
  const float* w1_1 = (const float*)d_in[11];
  const float* s1_1 = (const float*)d_in[12];
  const float* b1_1 = (const float*)d_in[13];

  float* out      = (float*)d_out;
  float* new_xyz  = out;                 // (B,P,3)
  float* feat_out = out + (size_t)B * P * 3;  // (B,192,P)

  char* w = (char*)d_ws;
  int* idx0 = (int*)w; w += (size_t)B * P * 16 * sizeof(int);
  int* idx1 = (int*)w; w += (size_t)B * P * 32 * sizeof(int);

  fps_kernel<<<dim3(B), dim3(1024), 0, stream>>>(xyz, new_xyz);
  ballq_kernel<<<dim3(B * P / 4), dim3(256), 0, stream>>>(xyz, new_xyz, idx0, idx1);
  mlp_kernel<16, 32, 64, 0><<<dim3(B * P / 8), dim3(256), 0, stream>>>(
      xyz, feats, new_xyz, idx0, w0_0, s0_0, b0_0, w0_1, s0_1, b0_1, feat_out);
  mlp_kernel<32, 64, 128, 64><<<dim3(B * P / 8), dim3(256), 0, stream>>>(
      xyz, feats, new_xyz, idx1, w1_0, s1_0, b1_0, w1_1, s1_1, b1_1, feat_out);
}

// Round 7
// 2284.543 us; speedup vs baseline: 1.0092x; 1.0092x over previous
//
#include <hip/hip_runtime.h>

#define B 8
#define N 16384
#define C_IN 32
#define P 1024

typedef float v2f __attribute__((ext_vector_type(2)));
typedef unsigned long long ull;

// ---------------------------------------------------------------------------
// FPS: one block per batch, 1024 threads, 16 points/thread as 8 index-pairs.
// R7: R5==R6 duration despite different math proved the pk win was eaten by
// (a) float4->v2f marshal movs, (b) b128 4-way bank conflicts (9506/iter),
// (c) serial ds_bpermute pair in the reduce. Cuts:
//  - direct v2f loads via ds_read_b64 (16 reads, conflict-free, 0 movs)
//  - xy-phase first (no cz dep), z-phase second -> scalar cz load covered
//  - reduce: 6 DPP fmax levels to lane 63 + v_readlane -> SGPR broadcast
//    (R4-proven ctrl codes), no bpermute.
// Kept from R5/R6 (proven): single barrier/iter, parity slots, key
//   key = (P-1-iter)<<46 | ~bits(val)<<14 | n  -> min-key == numpy first-max
// (ties exact), msel capture, coords re-read at end (original bits).
// Math bitwise == numpy: d = ((dx*dx+dy*dy)+dz*dz), all rn, x-c == x+(-c).
// Thread t owns n = 4t + 4096*i + e (i=0..3,e=0..3), s=4i+e ascending in n;
// strict '>' chain keeps smallest n per thread.
// ---------------------------------------------------------------------------
#define R8(OP) OP(0) OP(1) OP(2) OP(3) OP(4) OP(5) OP(6) OP(7)

__device__ __forceinline__ v2f pk_add(v2f a, v2f b) {
  v2f d; asm("v_pk_add_f32 %0, %1, %2" : "=v"(d) : "v"(a), "v"(b)); return d;
}
__device__ __forceinline__ v2f pk_mul(v2f a, v2f b) {
  v2f d; asm("v_pk_mul_f32 %0, %1, %2" : "=v"(d) : "v"(a), "v"(b)); return d;
}
__device__ __forceinline__ float negf(float x) {
  return __int_as_float(__float_as_int(x) ^ 0x80000000);
}

// one max-reduce level via DPP; ctrl codes proven in R4's passing kernel
template <int CTRL>
__device__ __forceinline__ float dpp_fmax(float v) {
  float o = __int_as_float(__builtin_amdgcn_update_dpp(
      __float_as_int(v), __float_as_int(v), CTRL, 0xF, 0xF, false));
  return fmaxf(v, o);
}

__global__ __launch_bounds__(1024)
void fps_kernel(const float* __restrict__ xyz, float* __restrict__ new_xyz)
{
  __shared__ __align__(16) float sx[N];      // 64 KiB
  __shared__ __align__(16) float sy[N];      // 64 KiB
  __shared__ ull slot[2];                    // argmax key, parity-alternating

  const int b = blockIdx.x;
  const int t = threadIdx.x;
  const float* xb = xyz + (size_t)b * (N * 3);

  if (t == 0) { slot[0] = ~0ull; slot[1] = ~0ull; }

  // pair j (j=0..7) = points {n0, n0+1}, n0 = 4t + 4096*(j>>1) + 2*(j&1)
#define FPS_DECL(j) v2f pzp##j, dmp##j; dmp##j.x = 1e10f; dmp##j.y = 1e10f;
  R8(FPS_DECL)
#define FPS_LOADP(j) {                                                         \
    const int n0 = (t << 2) + ((j >> 1) << 12) + ((j & 1) << 1);               \
    const float2 ld0 = *(const float2*)&xb[(size_t)n0 * 3 + 0]; /* x0,y0 */    \
    const float2 ld1 = *(const float2*)&xb[(size_t)n0 * 3 + 2]; /* z0,x1 */    \
    const float2 ld2 = *(const float2*)&xb[(size_t)n0 * 3 + 4]; /* y1,z1 */    \
    sx[n0]     = ld0.x;  sy[n0]     = ld0.y;                                   \
    sx[n0 + 1] = ld1.y;  sy[n0 + 1] = ld2.x;                                   \
    pzp##j.x   = ld1.x;  pzp##j.y   = ld2.y;                                   \
    asm volatile("" : "+v"(pzp##j)); }
  R8(FPS_LOADP)

  float cz = xb[2];                 // z of point 0
  __syncthreads();
  float cx = sx[0], cy = sy[0];
  int sel = 0, msel = 0;

  for (int iter = 0; iter < P; ++iter) {
    // thread `iter` records the selected index; coords re-read at the end
    msel = (t == iter) ? sel : msel;
    if (iter == P - 1) break;

    v2f cxx, cyy, czz;
    { float v = negf(cx); cxx.x = v; cxx.y = v; }
    { float v = negf(cy); cyy.x = v; cyy.y = v; }
    { float v = negf(cz); czz.x = v; czz.y = v; }

    // ---- xy phase: sq_j = dx*dx + dy*dy for all 8 pairs (no cz dep) ----
    v2f sq0, sq1, sq2, sq3, sq4, sq5, sq6, sq7;
#define FPS_XY(i, ja, jb) {                                                    \
      const int n0 = (t << 2) + ((i) << 12);                                   \
      v2f xl = *(const v2f*)&sx[n0];  v2f xh = *(const v2f*)&sx[n0 + 2];       \
      v2f yl = *(const v2f*)&sy[n0];  v2f yh = *(const v2f*)&sy[n0 + 2];       \
      v2f dxl = pk_add(xl, cxx), dyl = pk_add(yl, cyy);                        \
      v2f dxh = pk_add(xh, cxx), dyh = pk_add(yh, cyy);                        \
      sq##ja = pk_add(pk_mul(dxl, dxl), pk_mul(dyl, dyl));                     \
      sq##jb = pk_add(pk_mul(dxh, dxh), pk_mul(dyh, dyh)); }
    FPS_XY(0, 0, 1)
    FPS_XY(1, 2, 3)
    FPS_XY(2, 4, 5)
    FPS_XY(3, 6, 7)

    // ---- z phase + dmin + per-thread argmax (s = 2j, 2j+1 ascending n) ----
    float bestv = -1.0f;
    int   s = 0;
#define FPS_Z(j) {                                                             \
      v2f dz = pk_add(pzp##j, czz);                                            \
      v2f dd = pk_add(sq##j, pk_mul(dz, dz));                                  \
      dmp##j.x = fminf(dmp##j.x, dd.x);                                        \
      dmp##j.y = fminf(dmp##j.y, dd.y);                                        \
      bool b0 = dmp##j.x > bestv;                                              \
      bestv = b0 ? dmp##j.x : bestv;  s = b0 ? (2 * (j))     : s;              \
      bool b1 = dmp##j.y > bestv;                                              \
      bestv = b1 ? dmp##j.y : bestv;  s = b1 ? (2 * (j) + 1) : s; }
    R8(FPS_Z)

    // ---- value-only wave max: 6 DPP levels -> lane 63, readlane -> SGPR ----
    float wm = bestv;
    wm = dpp_fmax<0xB1>(wm);    // quad_perm xor1
    wm = dpp_fmax<0x4E>(wm);    // quad_perm xor2
    wm = dpp_fmax<0x141>(wm);   // row_half_mirror (xor4)
    wm = dpp_fmax<0x140>(wm);   // row_mirror (xor8)
    wm = dpp_fmax<0x142>(wm);   // row_bcast15: lane15->row1, lane47->row3
    wm = dpp_fmax<0x143>(wm);   // row_bcast31: lane31->rows 2,3
    const float wmax = __int_as_float(
        __builtin_amdgcn_readlane(__float_as_int(wm), 63));

    // candidates (>=1 lane/wave) race via order-encoding key; min key wins.
    if (bestv == wmax) {
      int nn = (t << 2) + ((s & 12) << 10) + (s & 3);        // 14 bits
      unsigned inv = ~__float_as_uint(bestv);                // desc in val
      ull key = ((ull)(unsigned)(P - 1 - iter) << 46) |
                ((ull)inv << 14) | (ull)(unsigned)nn;
      atomicMin(&slot[iter & 1], key);
    }
    __syncthreads();

    ull k = slot[iter & 1];
    sel = __builtin_amdgcn_readfirstlane((int)((unsigned)k & 0x3FFFu));
    cx = sx[sel];                   // uniform addr -> LDS broadcast
    cy = sy[sel];
    cz = xb[(size_t)sel * 3 + 2];   // uniform scalar load; consumed late
  }

  // thread t holds the selected index of iteration t; emit original bits
  {
    const int n = msel;
    size_t o = ((size_t)b * P + t) * 3;
    new_xyz[o + 0] = sx[n];
    new_xyz[o + 1] = sy[n];
    new_xyz[o + 2] = xb[(size_t)n * 3 + 2];
  }
#undef FPS_DECL
#undef FPS_LOADP
#undef FPS_XY
#undef FPS_Z
}

// ---------------------------------------------------------------------------
// Ball query, both radii in one pass. One wave per (b,p). Reproduces the
// reference's gemm-form dist2 bitwise: (qq + xx) - 2*((cx*x+cy*y)+cz*z).
// First-nsample-in-index-order via ballot + prefix popcount; pad = first hit.
// ---------------------------------------------------------------------------
__global__ __launch_bounds__(256) void ballq_kernel(
    const float* __restrict__ xyz, const float* __restrict__ new_xyz,
    int* __restrict__ idx0, int* __restrict__ idx1)
{
  const int wid  = blockIdx.x * 4 + (threadIdx.x >> 6);
  const int lane = threadIdx.x & 63;
  const int b = wid >> 10;
  const int p = wid & (P - 1);
  const float* xb = xyz + (size_t)b * (N * 3);
  const size_t bp = (size_t)b * P + p;
  const float cx = new_xyz[bp * 3 + 0];
  const float cy = new_xyz[bp * 3 + 1];
  const float cz = new_xyz[bp * 3 + 2];
  const float qv = __fadd_rn(__fadd_rn(__fmul_rn(cx, cx), __fmul_rn(cy, cy)),
                             __fmul_rn(cz, cz));
  int* __restrict__ o0 = idx0 + bp * 16;
  int* __restrict__ o1 = idx1 + bp * 32;

  int c0 = 0, c1 = 0, f0 = 0, f1 = 0;
  const unsigned long long below = (1ull << lane) - 1ull;

  for (int base = 0; base < N; base += 64) {
    int n = base + lane;
    float x = xb[n * 3 + 0], y = xb[n * 3 + 1], z = xb[n * 3 + 2];
    float xxv = __fadd_rn(__fadd_rn(__fmul_rn(x, x), __fmul_rn(y, y)),
                          __fmul_rn(z, z));
    float dot = __fadd_rn(__fadd_rn(__fmul_rn(cx, x), __fmul_rn(cy, y)),
                          __fmul_rn(cz, z));
    float d2 = __fsub_rn(__fadd_rn(qv, xxv), __fmul_rn(2.0f, dot));
    unsigned long long m0 = __ballot(d2 < 0.25f);
    unsigned long long m1 = __ballot(d2 < 1.0f);
    if (c0 == 0 && m0) f0 = base + __builtin_ctzll(m0);
    if (c1 == 0 && m1) f1 = base + __builtin_ctzll(m1);
    if ((m0 >> lane) & 1ull) {
      int pos = c0 + (int)__builtin_popcountll(m0 & below);
      if (pos < 16) o0[pos] = n;
    }
    if ((m1 >> lane) & 1ull) {
      int pos = c1 + (int)__builtin_popcountll(m1 & below);
      if (pos < 32) o1[pos] = n;
    }
    c0 = min(16, c0 + (int)__builtin_popcountll(m0));
    c1 = min(32, c1 + (int)__builtin_popcountll(m1));
    if (c0 >= 16 && c1 >= 32) break;
  }
  for (int s = c0 + lane; s < 16; s += 64) o0[s] = f0;
  for (int s = c1 + lane; s < 32; s += 64) o1[s] = f1;
}

// ---------------------------------------------------------------------------
// Fused grouping + conv1(+BN+ReLU) + conv2(+BN+ReLU) + max over samples.
// Block = 256 threads handles 8 points; weights staged in LDS once per block.
// out layout: (B, 192, P) at d_out + B*P*3, branch writes CH_OFF..CH_OFF+C2.
// ---------------------------------------------------------------------------
template <int S, int C1, int C2, int CH_OFF>
__global__ __launch_bounds__(256) void mlp_kernel(
    const float* __restrict__ xyz, const float* __restrict__ feats,
    const float* __restrict__ new_xyz, const int* __restrict__ idx,
    const float* __restrict__ w1, const float* __restrict__ s1,
    const float* __restrict__ b1, const float* __restrict__ w2,
    const float* __restrict__ s2, const float* __restrict__ b2,
    float* __restrict__ out)
{
  static_assert((C1 * S) % 256 == 0 && (C2 * S) % 256 == 0, "mapping");
  __shared__ float wl1[35][C1];     // wl1[c][o] = w1[o][c]
  __shared__ float wl2[C1][C2];     // wl2[c][o] = w2[o][c]
  __shared__ float sb1[2][C1];
  __shared__ float sb2[2][C2];
  __shared__ float xs[35][S];
  __shared__ float o1s[C1][S];
  __shared__ float pm[256];

  const int tid = threadIdx.x;
  for (int i = tid; i < 35 * C1; i += 256) {
    int o = i % C1, c = i / C1;
    wl1[c][o] = w1[o * 35 + c];
  }
  for (int i = tid; i < C1 * C2; i += 256) {
    int o = i % C2, c = i / C2;
    wl2[c][o] = w2[o * C1 + c];
  }
  if (tid < C1) { sb1[0][tid] = s1[tid]; sb1[1][tid] = b1[tid]; }
  if (tid < C2) { sb2[0][tid] = s2[tid]; sb2[1][tid] = b2[tid]; }

  const int b  = blockIdx.x / (P / 8);
  const int p0 = (blockIdx.x % (P / 8)) * 8;
  const float* xb = xyz + (size_t)b * (N * 3);
  const float* fb = feats + (size_t)b * (C_IN * N);
  __syncthreads();

  for (int pi = 0; pi < 8; ++pi) {
    const int p = p0 + pi;
    const size_t bp = (size_t)b * P + p;
    const int* ip = idx + bp * S;
    const float cx = new_xyz[bp * 3 + 0];
    const float cy = new_xyz[bp * 3 + 1];
    const float cz = new_xyz[bp * 3 + 2];
    // gather grouped input (35, S): xyz-diff channels 0..2, features 3..34
    for (int i = tid; i < 35 * S; i += 256) {
      int c = i / S, s = i % S;
      int n = ip[s];
      float v;
      if (c == 0)      v = xb[n * 3 + 0] - cx;
      else if (c == 1) v = xb[n * 3 + 1] - cy;
      else if (c == 2) v = xb[n * 3 + 2] - cz;
      else             v = fb[(size_t)(c - 3) * N + n];
      xs[c][s] = v;
    }
    __syncthreads();
    // layer 1: out1[o][s] = relu(dot(w1[o], x[:,s]) * s1[o] + b1[o])
    {
      constexpr int OPT = (C1 * S) / 256;
      const int s  = tid % S;
      const int ob = (tid / S) * OPT;
      float acc[OPT];
#pragma unroll
      for (int j = 0; j < OPT; ++j) acc[j] = 0.0f;
      for (int c = 0; c < 35; ++c) {
        float xv = xs[c][s];
#pragma unroll
        for (int j = 0; j < OPT; ++j) acc[j] = fmaf(xv, wl1[c][ob + j], acc[j]);
      }
#pragma unroll
      for (int j = 0; j < OPT; ++j) {
        float v = fmaf(acc[j], sb1[0][ob + j], sb1[1][ob + j]);
        o1s[ob + j][s] = fmaxf(v, 0.0f);
      }
    }
    __syncthreads();
    // layer 2 + max over s
    {
      constexpr int NS = (C2 * S) / 256;
      const int o2 = tid % C2;
      const int sb = (tid / C2) * NS;
      float acc[NS];
#pragma unroll
      for (int j = 0; j < NS; ++j) acc[j] = 0.0f;
      for (int c = 0; c < C1; ++c) {
        float wv = wl2[c][o2];
#pragma unroll
        for (int j = 0; j < NS; ++j) acc[j] = fmaf(wv, o1s[c][sb + j], acc[j]);
      }
      const float scale = sb2[0][o2], bias = sb2[1][o2];
      float m = 0.0f;  // relu floor: max over relu(v) == max(0, max v)
#pragma unroll
      for (int j = 0; j < NS; ++j) {
        float v = fmaf(acc[j], scale, bias);
        m = fmaxf(m, v);
      }
      pm[tid] = m;
      __syncthreads();
      if (tid < C2) {
        float mm = pm[tid];
#pragma unroll
        for (int g = 1; g < 256 / C2; ++g) mm = fmaxf(mm, pm[tid + g * C2]);
        out[((size_t)b * 192 + CH_OFF + tid) * P + p] = mm;
      }
    }
    __syncthreads();
  }
}

extern "C" void kernel_launch(void* const* d_in, const int* in_sizes, int n_in,
                              void* d_out, int out_size, void* d_ws, size_t ws_size,
                              hipStream_t stream) {
  const float* xyz   = (const float*)d_in[0];
  const float* feats = (const float*)d_in[1];
  const float* w0_0 = (const float*)d_in[2];
  const float* s0_0 = (const float*)d_in[3];
  const float* b0_0 = (const float*)d_in[4];
  const float* w0_1 = (const float*)d_in[5];
  const float* s0_1 = (const float*)d_in[6];
  const float* b0_1 = (const float*)d_in[7];
  const float* w1_0 = (const float*)d_in[8];
  const float* s1_0 = (const float*)d_in[9];
  const float* b1_0 = (const float*)d_in[10];
  const float* w1_1 = (const float*)d_in[11];
  const float* s1_1 = (const float*)d_in[12];
  const float* b1_1 = (const float*)d_in[13];

  float* out      = (float*)d_out;
  float* new_xyz  = out;                 // (B,P,3)
  float* feat_out = out + (size_t)B * P * 3;  // (B,192,P)

  char* w = (char*)d_ws;
  int* idx0 = (int*)w; w += (size_t)B * P * 16 * sizeof(int);
  int* idx1 = (int*)w; w += (size_t)B * P * 32 * sizeof(int);

  fps_kernel<<<dim3(B), dim3(1024), 0, stream>>>(xyz, new_xyz);
  ballq_kernel<<<dim3(B * P / 4), dim3(256), 0, stream>>>(xyz, new_xyz, idx0, idx1);
  mlp_kernel<16, 32, 64, 0><<<dim3(B * P / 8), dim3(256), 0, stream>>>(
      xyz, feats, new_xyz, idx0, w0_0, s0_0, b0_0, w0_1, s0_1, b0_1, feat_out);
  mlp_kernel<32, 64, 128, 64><<<dim3(B * P / 8), dim3(256), 0, stream>>>(
      xyz, feats, new_xyz, idx1, w1_0, s1_0, b1_0, w1_1, s1_1, b1_1, feat_out);
}